// Round 8
// baseline (140.163 us; speedup 1.0000x reference)
//
#include <hip/hip_runtime.h>
#include <hip/hip_bf16.h>

#define B_ 2
#define H_ 16
#define HKV_ 4
#define HPG_ 4      // heads per kv group
#define S_ 4096
#define D_ 64
#define BN_ 64
#define NB_ 64
#define BPQ_ 6
#define QSCALE_LOG2 0.18033688f   // (1/sqrt(64)) * log2(e)
#define LOG2E 1.44269504f
#define LDK 72      // padded LDS row stride (bf16 elems)
#define NSPLIT0 4   // qb==0 split factor
#define PART2_ 16896 // floats per (b,hkv,split) part: 4 heads*64*64 O + 256 m + 256 l

typedef short bf16x8 __attribute__((ext_vector_type(8)));
typedef short bf16x4v __attribute__((ext_vector_type(4)));
typedef float f32x4 __attribute__((ext_vector_type(4)));
typedef unsigned int u32x4 __attribute__((ext_vector_type(4)));

static __device__ __forceinline__ short f2bf(float f) {
    unsigned u = __builtin_bit_cast(unsigned, f);
    unsigned r = u + 0x7FFFu + ((u >> 16) & 1u);   // RNE (finite normals)
    return (short)(r >> 16);
}

static __device__ __forceinline__ unsigned cvt_pk_bf16(float lo, float hi) {
    unsigned r;
    asm("v_cvt_pk_bf16_f32 %0, %1, %2" : "=v"(r) : "v"(lo), "v"(hi));
    return r;   // low16 = bf16(lo), high16 = bf16(hi)
}

// One block = one (b, hkv, qb): 4 GQA heads share chunk list + K/V.
// 8 waves: head g = wave>>1, row-half = wave&1 (2 fragments of 16 q-rows).
// PAIRED chunk rounds: 2 chunks per barrier (4 LDS tile-sets, 2 pairs),
// halving the serial round count; QK(B) overlaps softmax(A) via TLP.
__global__ __launch_bounds__(512, 2) void sparse_attn_main(
    const float* __restrict__ q,
    const float* __restrict__ k,
    const float* __restrict__ v,
    const int* __restrict__ seg,
    const int* __restrict__ bidx,
    const float* __restrict__ slopes,
    float* __restrict__ out,
    float* __restrict__ ws)
{
    __shared__ __align__(16) short kc[4][BN_ * LDK];  // K tiles [key][d]
    __shared__ __align__(16) short vt[4][BN_ * LDK];  // V^T tiles [d][key^swz]
    __shared__ int vlist[17];
    __shared__ int vcount;

    const int qbx  = blockIdx.x;        // 0..NB_+2
    int qb, split;
    if (qbx < NB_) { qb = qbx; split = 0; }
    else           { qb = 0;   split = qbx - (NB_ - 1); }   // 64,65,66 -> 1,2,3
    const bool split_path = (qb == 0);

    const int y    = blockIdx.y;        // 0..7 = b*HKV+hkv
    const int b    = y / HKV_;
    const int hkv  = y % HKV_;
    const int tid  = threadIdx.x;
    const int wave = tid >> 6;
    const int g    = wave >> 1;         // head within GQA group
    const int half = wave & 1;          // which 32-row half of the q block
    const int lane = tid & 63;
    const int l16  = lane & 15;
    const int lhi  = lane >> 4;         // 0..3
    const int h    = hkv * HPG_ + g;

    const float slope2 = slopes[h] * LOG2E;
    const int   qseg   = seg[b * S_ + qb * BN_];

    // ---- valid-chunk list (lane-parallel, wave 0) ----
    if (wave == 0) {
        const int n = split_path ? 16 : (1 + BPQ_);
        int cand = -1;
        if (lane < n) {
            if (split_path)       cand = split + 4 * lane;
            else if (lane == 0)   cand = 0;                  // global block
            else                  cand = bidx[qb * BPQ_ + lane - 1];
        }
        bool ok = false;
        if (cand >= 0 && cand < NB_) {
            int ks_ = seg[b * S_ + cand * BN_];
            ok = (qseg >= 0) && (ks_ == qseg);
        }
        unsigned long long m = __ballot(ok);
        if (ok) {
            int rank = __popcll(m & ((1ull << lane) - 1ull));
            vlist[rank] = cand;
        }
        if (lane == 0) vcount = (int)__popcll(m);
    }

    // ---- Q fragments: 2 per wave (rows half*32 + j*16 + l16 of head h) ----
    bf16x8 qf[2][2];
    float qpos[2];
#pragma unroll
    for (int j = 0; j < 2; ++j) {
        const int qrow = qb * BN_ + half * 32 + j * 16 + l16;
        qpos[j] = (float)qrow;
        const float* qp = q + (((size_t)(b * H_ + h)) * S_ + qrow) * D_;
#pragma unroll
        for (int kk = 0; kk < 2; ++kk)
#pragma unroll
            for (int i = 0; i < 8; ++i)
                qf[j][kk][i] = f2bf(qp[kk * 32 + lhi * 8 + i] * QSCALE_LOG2);
    }

    // O^T accumulators: oacc[j][dt] reg r -> d = 16dt+4lhi+r, q-col = l16
    f32x4 oacc[2][4] = {};
    float mrun[2] = { -1e30f, -1e30f }, lrun[2] = { 0.f, 0.f };

    const float* kb_ptr = k + ((size_t)(b * HKV_ + hkv)) * S_ * D_;
    const float* vb_ptr = v + ((size_t)(b * HKV_ + hkv)) * S_ * D_;

    float4 kr0, kr1, vr0, vr1;
#define ISSUE_LOADS(CBLK) do { \
        const float4* ks_ = (const float4*)(kb_ptr + (size_t)(CBLK) * (BN_ * D_)); \
        const float4* vs_ = (const float4*)(vb_ptr + (size_t)(CBLK) * (BN_ * D_)); \
        kr0 = ks_[tid];       kr1 = ks_[tid + 512]; \
        vr0 = vs_[tid];       vr1 = vs_[tid + 512]; \
    } while (0)

    // idx = float4 index 0..1023; key = idx>>4, d0 = (idx&15)*4.
    // kc: packed b64 write. vt: 4 scalar writes, col XOR-swizzled by 8*((d>>2)&7).
#define WST1(P, IDX, KR, VR) do { \
        int key_ = (IDX) >> 4; \
        int d0_  = ((IDX) & 15) * 4; \
        uint2 kp_ = { cvt_pk_bf16(KR.x, KR.y), cvt_pk_bf16(KR.z, KR.w) }; \
        *(uint2*)&kc[P][key_ * LDK + d0_] = kp_; \
        int sw_ = key_ ^ (((d0_ >> 2) & 7) << 3); \
        vt[P][(d0_ + 0) * LDK + sw_] = f2bf(VR.x); \
        vt[P][(d0_ + 1) * LDK + sw_] = f2bf(VR.y); \
        vt[P][(d0_ + 2) * LDK + sw_] = f2bf(VR.z); \
        vt[P][(d0_ + 3) * LDK + sw_] = f2bf(VR.w); \
    } while (0)
#define WRITE_STAGE(P) do { WST1(P, tid, kr0, vr0); WST1(P, tid + 512, kr1, vr1); } while (0)

    // ---- one chunk's compute: QK^T -> online softmax -> PV, from LDS slot ----
#define COMPUTE(SLOT, KBASE) do { \
        f32x4 sacc[2][4] = {}; \
        _Pragma("unroll") \
        for (int nt = 0; nt < 4; ++nt) \
            _Pragma("unroll") \
            for (int kk = 0; kk < 2; ++kk) { \
                bf16x8 kf_ = *(const bf16x8*)&kc[SLOT][(nt * 16 + l16) * LDK + kk * 32 + lhi * 8]; \
                sacc[0][nt] = __builtin_amdgcn_mfma_f32_16x16x32_bf16(kf_, qf[0][kk], sacc[0][nt], 0, 0, 0); \
                sacc[1][nt] = __builtin_amdgcn_mfma_f32_16x16x32_bf16(kf_, qf[1][kk], sacc[1][nt], 0, 0, 0); \
            } \
        unsigned pk_[2][4][2]; \
        _Pragma("unroll") \
        for (int j = 0; j < 2; ++j) { \
            const float dbase = qpos[j] - (float)((KBASE) + lhi * 4); \
            float mx = -1e30f; \
            _Pragma("unroll") \
            for (int nt = 0; nt < 4; ++nt) \
                _Pragma("unroll") \
                for (int r2 = 0; r2 < 4; ++r2) { \
                    float sc = fmaf(-slope2, fabsf(dbase - (float)(nt * 16 + r2)), sacc[j][nt][r2]); \
                    sacc[j][nt][r2] = sc; \
                    mx = fmaxf(mx, sc); \
                } \
            mx = fmaxf(mx, __shfl_xor(mx, 16)); \
            mx = fmaxf(mx, __shfl_xor(mx, 32)); \
            const float mn = fmaxf(mrun[j], mx); \
            float sum = 0.f; \
            _Pragma("unroll") \
            for (int nt = 0; nt < 4; ++nt) { \
                float p0 = exp2f(sacc[j][nt][0] - mn); \
                float p1 = exp2f(sacc[j][nt][1] - mn); \
                float p2 = exp2f(sacc[j][nt][2] - mn); \
                float p3 = exp2f(sacc[j][nt][3] - mn); \
                sum += (p0 + p1) + (p2 + p3); \
                pk_[j][nt][0] = cvt_pk_bf16(p0, p1); \
                pk_[j][nt][1] = cvt_pk_bf16(p2, p3); \
            } \
            sum += __shfl_xor(sum, 16); \
            sum += __shfl_xor(sum, 32); \
            const float corr = exp2f(mrun[j] - mn); \
            mrun[j] = mn; \
            lrun[j] = lrun[j] * corr + sum; \
            _Pragma("unroll") \
            for (int dt = 0; dt < 4; ++dt) oacc[j][dt] *= corr; \
        } \
        _Pragma("unroll") \
        for (int kk = 0; kk < 2; ++kk) { \
            bf16x8 pf[2]; \
            _Pragma("unroll") \
            for (int j = 0; j < 2; ++j) { \
                u32x4 pw = { pk_[j][2 * kk][0], pk_[j][2 * kk][1], \
                             pk_[j][2 * kk + 1][0], pk_[j][2 * kk + 1][1] }; \
                pf[j] = __builtin_bit_cast(bf16x8, pw); \
            } \
            _Pragma("unroll") \
            for (int dt = 0; dt < 4; ++dt) { \
                const short* vrow = &vt[SLOT][(dt * 16 + l16) * LDK]; \
                const int sv8 = ((4 * dt + (l16 >> 2)) & 7) << 3; \
                bf16x4v lo = *(const bf16x4v*)&vrow[(kk * 32 + 4 * lhi) ^ sv8]; \
                bf16x4v hi = *(const bf16x4v*)&vrow[(kk * 32 + 16 + 4 * lhi) ^ sv8]; \
                bf16x8 vf = __builtin_shufflevector(lo, hi, 0, 1, 2, 3, 4, 5, 6, 7); \
                oacc[0][dt] = __builtin_amdgcn_mfma_f32_16x16x32_bf16(vf, pf[0], oacc[0][dt], 0, 0, 0); \
                oacc[1][dt] = __builtin_amdgcn_mfma_f32_16x16x32_bf16(vf, pf[1], oacc[1][dt], 0, 0, 0); \
            } \
        } \
    } while (0)

    __syncthreads();                    // vlist visible
    const int nval = vcount;            // >= 1 always

    // ---- prologue: stage pair 0 (slots 0,1), issue chunk 2 ----
    ISSUE_LOADS(vlist[0]);
    WRITE_STAGE(0);
    if (nval > 1) { ISSUE_LOADS(vlist[1]); WRITE_STAGE(1); }
    if (nval > 2) ISSUE_LOADS(vlist[2]);
    __syncthreads();                    // pair 0 ready

    const int nr = (nval + 1) >> 1;     // paired rounds
    for (int r = 0; r < nr; ++r) {
        const int p  = r & 1;
        const int s0 = 2 * p, s1 = 2 * p + 1;
        const int t0 = 2 * (p ^ 1), t1 = 2 * (p ^ 1) + 1;
        const int c0 = 2 * r, c1 = 2 * r + 1;

        if (c0 + 2 < nval) WRITE_STAGE(t0);           // regs issued last round
        if (c0 + 3 < nval) ISSUE_LOADS(vlist[c0 + 3]); // lands during COMPUTE(c0)

        COMPUTE(s0, vlist[c0] * BN_);

        if (c0 + 3 < nval) WRITE_STAGE(t1);
        if (c0 + 4 < nval) ISSUE_LOADS(vlist[c0 + 4]); // lands during COMPUTE(c1)+barrier

        if (c1 < nval) COMPUTE(s1, vlist[c1] * BN_);

        __syncthreads();    // pair p readers done; pair p^1 writes visible
    }

    // ---- epilogue ----
    if (split_path) {
        float* wsp = ws + (size_t)((b * HKV_ + hkv) * NSPLIT0 + split) * PART2_;
#pragma unroll
        for (int j = 0; j < 2; ++j) {
            const int row = half * 32 + j * 16 + l16;
#pragma unroll
            for (int dt = 0; dt < 4; ++dt) {
                float4 o4 = { oacc[j][dt][0], oacc[j][dt][1], oacc[j][dt][2], oacc[j][dt][3] };
                *(float4*)&wsp[g * 4096 + row * 64 + dt * 16 + 4 * lhi] = o4;   // unnormalized
            }
            if (lhi == 0) {
                wsp[16384 + g * 64 + row] = mrun[j];   // log2 domain
                wsp[16640 + g * 64 + row] = lrun[j];
            }
        }
    } else {
#pragma unroll
        for (int j = 0; j < 2; ++j) {
            const float inv = 1.0f / (lrun[j] == 0.f ? 1.f : lrun[j]);
            float* op = out + (((size_t)(b * H_ + h)) * S_ + qb * BN_ + half * 32 + j * 16 + l16) * D_;
#pragma unroll
            for (int dt = 0; dt < 4; ++dt) {
                float4 o4 = { oacc[j][dt][0] * inv, oacc[j][dt][1] * inv,
                              oacc[j][dt][2] * inv, oacc[j][dt][3] * inv };
                *(float4*)&op[dt * 16 + 4 * lhi] = o4;
            }
        }
    }
}

__global__ __launch_bounds__(256) void sparse_attn_combine(
    const float* __restrict__ ws,
    float* __restrict__ out)
{
    const int bh  = blockIdx.x;          // 0..31
    const int b   = bh / H_;
    const int h   = bh % H_;
    const int hkv = h >> 2;
    const int g   = h & 3;
    const int t   = threadIdx.x;
    const int row = t >> 2;              // 0..63
    const int d0  = (t & 3) * 16;

    const float* base = ws + (size_t)(b * HKV_ + hkv) * NSPLIT0 * PART2_;
    float ms[NSPLIT0], ls[NSPLIT0];
    float M = -1e30f;
#pragma unroll
    for (int s = 0; s < NSPLIT0; ++s) {
        ms[s] = base[s * PART2_ + 16384 + g * 64 + row];
        ls[s] = base[s * PART2_ + 16640 + g * 64 + row];
        M = fmaxf(M, ms[s]);
    }
    float w[NSPLIT0];
    float L = 0.f;
#pragma unroll
    for (int s = 0; s < NSPLIT0; ++s) {
        w[s] = exp2f(ms[s] - M);        // log2 domain
        L += w[s] * ls[s];
    }
    const float inv = 1.0f / (L == 0.f ? 1.f : L);

    float* op = out + ((size_t)bh * S_ + row) * D_ + d0;
#pragma unroll
    for (int jj = 0; jj < 16; ++jj) {
        float acc = 0.f;
#pragma unroll
        for (int s = 0; s < NSPLIT0; ++s)
            acc += w[s] * base[s * PART2_ + g * 4096 + row * 64 + d0 + jj];
        op[jj] = acc * inv;
    }
}

extern "C" void kernel_launch(void* const* d_in, const int* in_sizes, int n_in,
                              void* d_out, int out_size, void* d_ws, size_t ws_size,
                              hipStream_t stream) {
    const float* q      = (const float*)d_in[0];
    const float* k      = (const float*)d_in[1];
    const float* v      = (const float*)d_in[2];
    const int*   seg    = (const int*)d_in[3];
    const int*   bidx   = (const int*)d_in[4];
    const float* slopes = (const float*)d_in[5];
    float*       out    = (float*)d_out;
    float*       ws     = (float*)d_ws;

    dim3 grid(NB_ + (NSPLIT0 - 1), B_ * HKV_);
    sparse_attn_main<<<grid, 512, 0, stream>>>(q, k, v, seg, bidx, slopes, out, ws);
    sparse_attn_combine<<<dim3(B_ * H_), 256, 0, stream>>>(ws, out);
}

// Round 9
// 138.741 us; speedup vs baseline: 1.0103x; 1.0103x over previous
//
#include <hip/hip_runtime.h>
#include <hip/hip_bf16.h>

#define B_ 2
#define H_ 16
#define HKV_ 4
#define HPG_ 4      // heads per kv group
#define S_ 4096
#define D_ 64
#define BN_ 64
#define NB_ 64
#define BPQ_ 6
#define QSCALE_LOG2 0.18033688f   // (1/sqrt(64)) * log2(e)
#define LOG2E 1.44269504f
#define LDK 72      // padded LDS row stride (bf16 elems)
#define NSPLIT0 4   // qb==0 split factor
#define PART2_ 16896 // floats per (b,hkv,split) part: 4 heads*64*64 O + 256 m + 256 l

typedef short bf16x8 __attribute__((ext_vector_type(8)));
typedef short bf16x4v __attribute__((ext_vector_type(4)));
typedef float f32x4 __attribute__((ext_vector_type(4)));
typedef unsigned int u32x4 __attribute__((ext_vector_type(4)));

static __device__ __forceinline__ short f2bf(float f) {
    unsigned u = __builtin_bit_cast(unsigned, f);
    unsigned r = u + 0x7FFFu + ((u >> 16) & 1u);   // RNE (finite normals)
    return (short)(r >> 16);
}

static __device__ __forceinline__ unsigned cvt_pk_bf16(float lo, float hi) {
    unsigned r;
    asm("v_cvt_pk_bf16_f32 %0, %1, %2" : "=v"(r) : "v"(lo), "v"(hi));
    return r;   // low16 = bf16(lo), high16 = bf16(hi)
}

// One block = one (b, hkv, qb): all 4 GQA heads share the chunk list and K/V.
// 8 waves: wave -> head g = wave>>1, row-half = wave&1 (32 q rows per wave).
// K/V double-buffered in LDS; R7 loop structure.
// Occupancy: NO launch_bounds second arg (R7's (512,2) acted as a ~1-block/CU
// residency cap -> occ 14%). waves_per_eu(2,8): min 2 (VGPR cap 256, no R6
// spill), max 8 (no cap).
__global__ __launch_bounds__(512) __attribute__((amdgpu_waves_per_eu(2, 8)))
void sparse_attn_main(
    const float* __restrict__ q,
    const float* __restrict__ k,
    const float* __restrict__ v,
    const int* __restrict__ seg,
    const int* __restrict__ bidx,
    const float* __restrict__ slopes,
    float* __restrict__ out,
    float* __restrict__ ws)
{
    __shared__ __align__(16) short kc[2][BN_ * LDK];  // K tiles [key][d]
    __shared__ __align__(16) short vt[2][BN_ * LDK];  // V^T tiles [d][key^swz]
    __shared__ int vlist[17];
    __shared__ int vcount;

    const int qbx  = blockIdx.x;        // 0..NB_+2
    int qb, split;
    if (qbx < NB_) { qb = qbx; split = 0; }
    else           { qb = 0;   split = qbx - (NB_ - 1); }   // 64,65,66 -> 1,2,3
    const bool split_path = (qb == 0);

    const int y    = blockIdx.y;        // 0..7 = b*HKV+hkv
    const int b    = y / HKV_;
    const int hkv  = y % HKV_;
    const int tid  = threadIdx.x;
    const int wave = tid >> 6;
    const int g    = wave >> 1;         // head within GQA group
    const int half = wave & 1;          // which 32-row half of the q block
    const int lane = tid & 63;
    const int l16  = lane & 15;
    const int lhi  = lane >> 4;         // 0..3
    const int h    = hkv * HPG_ + g;

    const float slope2 = slopes[h] * LOG2E;
    const int   qseg   = seg[b * S_ + qb * BN_];

    // ---- valid-chunk list (lane-parallel, wave 0) ----
    if (wave == 0) {
        const int n = split_path ? 16 : (1 + BPQ_);
        int cand = -1;
        if (lane < n) {
            if (split_path)       cand = split + 4 * lane;
            else if (lane == 0)   cand = 0;                  // global block
            else                  cand = bidx[qb * BPQ_ + lane - 1];
        }
        bool ok = false;
        if (cand >= 0 && cand < NB_) {
            int ks_ = seg[b * S_ + cand * BN_];
            ok = (qseg >= 0) && (ks_ == qseg);
        }
        unsigned long long m = __ballot(ok);
        if (ok) {
            int rank = __popcll(m & ((1ull << lane) - 1ull));
            vlist[rank] = cand;
        }
        if (lane == 0) vcount = (int)__popcll(m);
    }

    // ---- Q fragments: 2 per wave (rows half*32 + j*16 + l16 of head h) ----
    bf16x8 qf[2][2];
    float qpos[2];
#pragma unroll
    for (int j = 0; j < 2; ++j) {
        const int qrow = qb * BN_ + half * 32 + j * 16 + l16;
        qpos[j] = (float)qrow;
        const float4* qp4 = (const float4*)(q + (((size_t)(b * H_ + h)) * S_ + qrow) * D_);
#pragma unroll
        for (int kk = 0; kk < 2; ++kk) {
            float4 a = qp4[kk * 8 + lhi * 2];
            float4 c = qp4[kk * 8 + lhi * 2 + 1];
            qf[j][kk][0] = f2bf(a.x * QSCALE_LOG2);
            qf[j][kk][1] = f2bf(a.y * QSCALE_LOG2);
            qf[j][kk][2] = f2bf(a.z * QSCALE_LOG2);
            qf[j][kk][3] = f2bf(a.w * QSCALE_LOG2);
            qf[j][kk][4] = f2bf(c.x * QSCALE_LOG2);
            qf[j][kk][5] = f2bf(c.y * QSCALE_LOG2);
            qf[j][kk][6] = f2bf(c.z * QSCALE_LOG2);
            qf[j][kk][7] = f2bf(c.w * QSCALE_LOG2);
        }
    }

    // O^T accumulators: oacc[j][dt] reg r -> d = 16dt+4lhi+r, q-col = l16
    f32x4 oacc[2][4] = {};
    float mrun[2] = { -1e30f, -1e30f }, lrun[2] = { 0.f, 0.f };

    const float* kb_ptr = k + ((size_t)(b * HKV_ + hkv)) * S_ * D_;
    const float* vb_ptr = v + ((size_t)(b * HKV_ + hkv)) * S_ * D_;

    float4 kr0, kr1, vr0, vr1;
#define ISSUE_LOADS(CBLK) do { \
        const float4* ks_ = (const float4*)(kb_ptr + (size_t)(CBLK) * (BN_ * D_)); \
        const float4* vs_ = (const float4*)(vb_ptr + (size_t)(CBLK) * (BN_ * D_)); \
        kr0 = ks_[tid];       kr1 = ks_[tid + 512]; \
        vr0 = vs_[tid];       vr1 = vs_[tid + 512]; \
    } while (0)

    // idx = float4 index 0..1023; key = idx>>4, d0 = (idx&15)*4.
    // kc: packed b64 write. vt: 4 scalar writes, col XOR-swizzled by 8*((d>>2)&7).
#define WST1(P, IDX, KR, VR) do { \
        int key_ = (IDX) >> 4; \
        int d0_  = ((IDX) & 15) * 4; \
        uint2 kp_ = { cvt_pk_bf16(KR.x, KR.y), cvt_pk_bf16(KR.z, KR.w) }; \
        *(uint2*)&kc[P][key_ * LDK + d0_] = kp_; \
        int sw_ = key_ ^ (((d0_ >> 2) & 7) << 3); \
        vt[P][(d0_ + 0) * LDK + sw_] = f2bf(VR.x); \
        vt[P][(d0_ + 1) * LDK + sw_] = f2bf(VR.y); \
        vt[P][(d0_ + 2) * LDK + sw_] = f2bf(VR.z); \
        vt[P][(d0_ + 3) * LDK + sw_] = f2bf(VR.w); \
    } while (0)
#define WRITE_STAGE(P) do { WST1(P, tid, kr0, vr0); WST1(P, tid + 512, kr1, vr1); } while (0)

    __syncthreads();                    // vlist visible
    const int nval = vcount;            // >= 1 always

    ISSUE_LOADS(vlist[0]);
    WRITE_STAGE(0);
    if (nval > 1) ISSUE_LOADS(vlist[1]);
    __syncthreads();                    // buf0 ready

    for (int c = 0; c < nval; ++c) {
        const int p = c & 1;
        const int kbase = vlist[c] * BN_;

        if (c + 1 < nval) {
            WRITE_STAGE(p ^ 1);                           // regs -> other buffer
            if (c + 2 < nval) ISSUE_LOADS(vlist[c + 2]);  // prefetch ahead
        }

        // ---- swapped QK^T: S^T = K * Q^T, K-fragments shared across j ----
        f32x4 sacc[2][4] = {};
#pragma unroll
        for (int nt = 0; nt < 4; ++nt)
#pragma unroll
            for (int kk = 0; kk < 2; ++kk) {
                bf16x8 kf_ = *(const bf16x8*)&kc[p][(nt * 16 + l16) * LDK + kk * 32 + lhi * 8];
                sacc[0][nt] = __builtin_amdgcn_mfma_f32_16x16x32_bf16(kf_, qf[0][kk], sacc[0][nt], 0, 0, 0);
                sacc[1][nt] = __builtin_amdgcn_mfma_f32_16x16x32_bf16(kf_, qf[1][kk], sacc[1][nt], 0, 0, 0);
            }

        // ---- online softmax (log2 domain); pack P->bf16 inline to free sacc ----
        unsigned pk_[2][4][2];
#pragma unroll
        for (int j = 0; j < 2; ++j) {
            const float dbase = qpos[j] - (float)(kbase + lhi * 4);
            float mx = -1e30f;
#pragma unroll
            for (int nt = 0; nt < 4; ++nt)
#pragma unroll
                for (int r2 = 0; r2 < 4; ++r2) {
                    float sc = fmaf(-slope2, fabsf(dbase - (float)(nt * 16 + r2)), sacc[j][nt][r2]);
                    sacc[j][nt][r2] = sc;
                    mx = fmaxf(mx, sc);
                }
            mx = fmaxf(mx, __shfl_xor(mx, 16));
            mx = fmaxf(mx, __shfl_xor(mx, 32));
            const float mn = fmaxf(mrun[j], mx);
            float sum = 0.f;
#pragma unroll
            for (int nt = 0; nt < 4; ++nt) {
                float p0 = exp2f(sacc[j][nt][0] - mn);
                float p1 = exp2f(sacc[j][nt][1] - mn);
                float p2 = exp2f(sacc[j][nt][2] - mn);
                float p3 = exp2f(sacc[j][nt][3] - mn);
                sum += (p0 + p1) + (p2 + p3);
                pk_[j][nt][0] = cvt_pk_bf16(p0, p1);
                pk_[j][nt][1] = cvt_pk_bf16(p2, p3);
            }
            sum += __shfl_xor(sum, 16);
            sum += __shfl_xor(sum, 32);
            const float corr = exp2f(mrun[j] - mn);
            mrun[j] = mn;
            lrun[j] = lrun[j] * corr + sum;
#pragma unroll
            for (int dt = 0; dt < 4; ++dt) oacc[j][dt] *= corr;
        }

        // ---- PV: O^T += V^T * P^T (k-slot perm: key = 32kk+16(i>>2)+4lhi+(i&3)) ----
#pragma unroll
        for (int kk = 0; kk < 2; ++kk) {
            bf16x8 pf[2];
#pragma unroll
            for (int j = 0; j < 2; ++j) {
                u32x4 pw = { pk_[j][2 * kk][0], pk_[j][2 * kk][1],
                             pk_[j][2 * kk + 1][0], pk_[j][2 * kk + 1][1] };
                pf[j] = __builtin_bit_cast(bf16x8, pw);
            }
#pragma unroll
            for (int dt = 0; dt < 4; ++dt) {
                const short* vrow = &vt[p][(dt * 16 + l16) * LDK];
                const int sv8 = ((4 * dt + (l16 >> 2)) & 7) << 3;
                bf16x4v lo = *(const bf16x4v*)&vrow[(kk * 32 + 4 * lhi) ^ sv8];
                bf16x4v hi = *(const bf16x4v*)&vrow[(kk * 32 + 16 + 4 * lhi) ^ sv8];
                bf16x8 vf = __builtin_shufflevector(lo, hi, 0, 1, 2, 3, 4, 5, 6, 7);
                oacc[0][dt] = __builtin_amdgcn_mfma_f32_16x16x32_bf16(vf, pf[0], oacc[0][dt], 0, 0, 0);
                oacc[1][dt] = __builtin_amdgcn_mfma_f32_16x16x32_bf16(vf, pf[1], oacc[1][dt], 0, 0, 0);
            }
        }

        __syncthreads();    // all readers of buf[p] done; buf[p^1] writes visible
    }

    // ---- epilogue ----
    if (split_path) {
        float* wsp = ws + (size_t)((b * HKV_ + hkv) * NSPLIT0 + split) * PART2_;
#pragma unroll
        for (int j = 0; j < 2; ++j) {
            const int row = half * 32 + j * 16 + l16;
#pragma unroll
            for (int dt = 0; dt < 4; ++dt) {
                float4 o4 = { oacc[j][dt][0], oacc[j][dt][1], oacc[j][dt][2], oacc[j][dt][3] };
                *(float4*)&wsp[g * 4096 + row * 64 + dt * 16 + 4 * lhi] = o4;   // unnormalized
            }
            if (lhi == 0) {
                wsp[16384 + g * 64 + row] = mrun[j];   // log2 domain
                wsp[16640 + g * 64 + row] = lrun[j];
            }
        }
    } else {
#pragma unroll
        for (int j = 0; j < 2; ++j) {
            const float inv = 1.0f / (lrun[j] == 0.f ? 1.f : lrun[j]);
            float* op = out + (((size_t)(b * H_ + h)) * S_ + qb * BN_ + half * 32 + j * 16 + l16) * D_;
#pragma unroll
            for (int dt = 0; dt < 4; ++dt) {
                float4 o4 = { oacc[j][dt][0] * inv, oacc[j][dt][1] * inv,
                              oacc[j][dt][2] * inv, oacc[j][dt][3] * inv };
                *(float4*)&op[dt * 16 + 4 * lhi] = o4;
            }
        }
    }
}

__global__ __launch_bounds__(256) void sparse_attn_combine(
    const float* __restrict__ ws,
    float* __restrict__ out)
{
    const int bh  = blockIdx.x;          // 0..31
    const int b   = bh / H_;
    const int h   = bh % H_;
    const int hkv = h >> 2;
    const int g   = h & 3;
    const int t   = threadIdx.x;
    const int row = t >> 2;              // 0..63
    const int d0  = (t & 3) * 16;

    const float* base = ws + (size_t)(b * HKV_ + hkv) * NSPLIT0 * PART2_;
    float ms[NSPLIT0], ls[NSPLIT0];
    float M = -1e30f;
#pragma unroll
    for (int s = 0; s < NSPLIT0; ++s) {
        ms[s] = base[s * PART2_ + 16384 + g * 64 + row];
        ls[s] = base[s * PART2_ + 16640 + g * 64 + row];
        M = fmaxf(M, ms[s]);
    }
    float w[NSPLIT0];
    float L = 0.f;
#pragma unroll
    for (int s = 0; s < NSPLIT0; ++s) {
        w[s] = exp2f(ms[s] - M);        // log2 domain
        L += w[s] * ls[s];
    }
    const float inv = 1.0f / (L == 0.f ? 1.f : L);

    float* op = out + ((size_t)bh * S_ + row) * D_ + d0;
#pragma unroll
    for (int jj = 0; jj < 16; ++jj) {
        float acc = 0.f;
#pragma unroll
        for (int s = 0; s < NSPLIT0; ++s)
            acc += w[s] * base[s * PART2_ + g * 4096 + row * 64 + d0 + jj];
        op[jj] = acc * inv;
    }
}

extern "C" void kernel_launch(void* const* d_in, const int* in_sizes, int n_in,
                              void* d_out, int out_size, void* d_ws, size_t ws_size,
                              hipStream_t stream) {
    const float* q      = (const float*)d_in[0];
    const float* k      = (const float*)d_in[1];
    const float* v      = (const float*)d_in[2];
    const int*   seg    = (const int*)d_in[3];
    const int*   bidx   = (const int*)d_in[4];
    const float* slopes = (const float*)d_in[5];
    float*       out    = (float*)d_out;
    float*       ws     = (float*)d_ws;

    dim3 grid(NB_ + (NSPLIT0 - 1), B_ * HKV_);
    sparse_attn_main<<<grid, 512, 0, stream>>>(q, k, v, seg, bidx, slopes, out, ws);
    sparse_attn_combine<<<dim3(B_ * H_), 256, 0, stream>>>(ws, out);
}